// Round 11
// baseline (222.563 us; speedup 1.0000x reference)
//
#include <hip/hip_runtime.h>
#include <hip/hip_fp16.h>
#include <math.h>

// Problem constants
#define BB   2
#define CSN  128
#define CDN  128
#define SD   8
#define SH   16
#define SW   16
#define DD   16
#define DH   32
#define DW   32
#define PP   (DD*DH*DW)   // 16384
#define GG   8
#define K3   27
#define OO   648

typedef _Float16 half8 __attribute__((ext_vector_type(8)));
typedef float f32x4 __attribute__((ext_vector_type(4)));

// ---------------------------------------------------------------------------
// Kernel 1: PREP — upsample + weight packs (identical to R10).
// ---------------------------------------------------------------------------
__global__ __launch_bounds__(256) void prep_kernel(
    const float* __restrict__ src, const float* __restrict__ wof,
    const float* __restrict__ wdcn, half8* __restrict__ uph8,
    half8* __restrict__ woxg, half8* __restrict__ wtx2)
{
    __shared__ float slab[2 * 8 * 16 * 17];
    const int bid = blockIdx.x;
    const int tid = threadIdx.x;

    if (bid < 512) {
        const int zo = bid & 15, pl = bid >> 4;
        const int h = pl & 1, g = (pl >> 1) & 7, b = pl >> 4;
        const int z0 = (zo - 1) >> 1;
        const float fz = (zo & 1) ? 0.25f : 0.75f;
        {
            const int zi = tid >> 7, cc = (tid >> 4) & 7, y = tid & 15;
            const int zsrc = min(max(z0 + zi, 0), SD - 1);
            const float* srow = src +
                (((size_t)(b * CSN + g * 16 + h * 8 + cc) * SD + zsrc) * SH + y) * SW;
            float* drow = &slab[((zi * 8 + cc) * 16 + y) * 17];
            *(float4*)(drow)      = *(const float4*)(srow);
            *(float4*)(drow + 4)  = *(const float4*)(srow + 4);
            *(float4*)(drow + 8)  = *(const float4*)(srow + 8);
            *(float4*)(drow + 12) = *(const float4*)(srow + 12);
        }
        __syncthreads();

        const float wz0 = 1.f - fz, wz1 = fz;
#pragma unroll 1
        for (int i = 0; i < 4; ++i) {
            const int pp = tid + i * 256;
            const int yo = pp >> 5, xo = pp & 31;
            const int y0 = (yo - 1) >> 1;
            const float fy = (yo & 1) ? 0.25f : 0.75f;
            const int ys0 = max(y0, 0), ys1 = min(y0 + 1, SH - 1);
            const int x0 = (xo - 1) >> 1;
            const float fx = (xo & 1) ? 0.25f : 0.75f;
            const int xs0 = max(x0, 0), xs1 = min(x0 + 1, SW - 1);
            const float w00 = (1.f - fy) * (1.f - fx), w01 = (1.f - fy) * fx;
            const float w10 = fy * (1.f - fx),         w11 = fy * fx;
            const int a00 = ys0 * 17 + xs0, a01 = ys0 * 17 + xs1;
            const int a10 = ys1 * 17 + xs0, a11 = ys1 * 17 + xs1;

            half8 hv;
#pragma unroll
            for (int cc = 0; cc < 8; ++cc) {
                const float* pa = &slab[(cc * 16) * 17];
                const float* pb = &slab[((8 + cc) * 16) * 17];
                const float s0 = w00 * pa[a00] + w01 * pa[a01]
                               + w10 * pa[a10] + w11 * pa[a11];
                const float s1 = w00 * pb[a00] + w01 * pb[a01]
                               + w10 * pb[a10] + w11 * pb[a11];
                hv[cc] = (_Float16)(wz0 * s0 + wz1 * s1);
            }
            uph8[(size_t)pl * PP + zo * 1024 + pp] = hv;
        }
    } else if (bid < 608) {
        const int i = (bid - 512) * 256 + tid;     // < 24576
        const int q = i & 3, lo = (i >> 2) & 15;
        const int t6 = i >> 6;
        const int ot = t6 % 6;
        const int gc0 = t6 / 6;
        const int c0 = gc0 & 7, g = gc0 >> 3;
        const int m = ot * 16 + lo;
        half8 hv;
#pragma unroll
        for (int j = 0; j < 8; ++j) hv[j] = (_Float16)0.0f;
        if (m < 81) {
            const int o = g * 81 + m;
            const int c = c0 * 32 + q * 8;
            const float sc = (c >= 128) ? 2.0f : 1.0f;
            const float* wr = wof + (size_t)o * 256 + c;
#pragma unroll
            for (int j = 0; j < 8; ++j) hv[j] = (_Float16)(wr[j] * sc);
        }
        woxg[i] = hv;
    } else {
        const int i = (bid - 608) * 256 + tid;     // < 57344
        const int q = i & 3, lo = (i >> 2) & 15, ot = (i >> 6) & 7;
        const int gp = i >> 9;
        const int pair = gp % 14, g = gp / 14;
        const int tap = pair * 2 + (q >> 1);
        half8 hv;
#pragma unroll
        for (int j = 0; j < 8; ++j) hv[j] = (_Float16)0.0f;
        if (tap < K3) {
            const int o = ot * 16 + lo;
            const int cb = g * 16 + (q & 1) * 8;
            const float* wr = wdcn + ((size_t)(o * CSN + cb)) * K3 + tap;
#pragma unroll
            for (int j = 0; j < 8; ++j) hv[j] = (_Float16)wr[(size_t)j * K3];
        }
        wtx2[i] = hv;
    }
}

// ---------------------------------------------------------------------------
// Kernel 2: MEGA — 4x4x4 cube tile per block, 2 blocks/CU.
// R11: region half-placement swizzled (v*32 + 16*((h^(v>>2))&1)) so gather
// and staging b128 ops spread across all 8 LDS bank-groups.
// LDS: catx 32K | region 28.8K | offls(10.4K) aliased w/ sampx dbuf (17K).
// ---------------------------------------------------------------------------
#define REGB_OFF 32768
#define SH2_OFF  61568
#define LDS_TOTAL 78976
#define SROW 68                 // padded sampx row stride (half8)

__global__ __launch_bounds__(512, 4) void mega_kernel(
    const float* __restrict__ dst, const float4* __restrict__ up4,
    const half8* __restrict__ woxg, const half8* __restrict__ wtx2,
    float* __restrict__ out)
{
    __shared__ __align__(16) char ldsraw[LDS_TOTAL];
    half8* catx = (half8*)ldsraw;
    char* regB = ldsraw + REGB_OFF;
    _Float16* offls = (_Float16*)(ldsraw + SH2_OFF);
    half8* sampx = (half8*)(ldsraw + SH2_OFF);   // dbuf: +0 / +544 half8

    const int tid = threadIdx.x;
    const int b = blockIdx.y;
    const int cb = blockIdx.x;
    const int X4 = (cb & 7) << 2, Y4 = ((cb >> 3) & 7) << 2, Z4 = (cb >> 6) << 2;

    // ---- phase 0: stage catx with cube columns ----
    {
        const int co = tid >> 4, pq = tid & 15;
        const int cz = pq >> 2, cy = pq & 3;
        const int pbase = ((Z4 + cz) << 10) + ((Y4 + cy) << 5) + X4;
        if (co < 16) {                      // dst channels, fp32 -> f16
            const int c = co * 8;
            const float* dp = dst + ((size_t)(b * CDN + c) << 14) + pbase;
            float vv[32];
#pragma unroll
            for (int j = 0; j < 8; ++j)
                *(float4*)&vv[j * 4] = *(const float4*)(dp + ((size_t)j << 14));
#pragma unroll
            for (int i = 0; i < 4; ++i) {
                half8 hh;
#pragma unroll
                for (int j = 0; j < 8; ++j) hh[j] = (_Float16)vv[j * 4 + i];
                catx[co * 64 + pq * 4 + i] = hh;
            }
        } else {                            // upsampled halves: f16 copy
            const int g2 = (co - 16) >> 1, oct = (co - 16) & 1;
            const half8* u8 = (const half8*)up4;
            const size_t base =
                ((size_t)((b * GG + g2) * 2 + oct) << 14) + pbase;
#pragma unroll
            for (int i = 0; i < 4; ++i)
                catx[co * 64 + pq * 4 + i] = u8[base + i];
        }
    }

    const int w = tid >> 6, l = tid & 63, lo = l & 15, q = l >> 4;
    const int t2 = w >> 1, h = w & 1;       // sampling: tap-in-round, ch-half
    const int tp = l;                       // cube column
    const int cz = tp >> 4, cy = (tp >> 2) & 3, cx = tp & 3;
    const int zoA = Z4 + cz, yoA = Y4 + cy, xoA = X4 + cx;

    f32x4 acc[4];
#pragma unroll
    for (int ps = 0; ps < 4; ++ps) acc[ps] = (f32x4){0.f, 0.f, 0.f, 0.f};

#pragma unroll 1
    for (int g = 0; g < 8; ++g) {
        __syncthreads();    // prior rounds done reading regB / sampx(offls)

        // ---- region staging: 9z x 10y x 10x voxels x 2 halves, swizzled ----
#pragma unroll 1
        for (int c = tid; c < 1800; c += 512) {
            const int hf = (c >= 900) ? 1 : 0;
            const int v = c - hf * 900;
            const int zz = v / 100, r2 = v - zz * 100;
            const int yy = r2 / 10, xx = r2 - yy * 10;
            const int vz = min(max(Z4 - 3 + zz, 0), DD - 1);
            const int vy = min(max(Y4 - 3 + yy, 0), DH - 1);
            const int vx = min(max(X4 - 3 + xx, 0), DW - 1);
            const float4 val =
                up4[(size_t)((b * GG + g) * 2 + hf) * PP +
                    (vz << 10) + (vy << 5) + vx];
            const int sw = (hf ^ (v >> 2)) & 1;          // bank-group swizzle
            *(float4*)(regB + v * 32 + sw * 16) = val;
        }

        // ---- phase A: offset mini-GEMM, A reused across all 4 ps ----
        if (w < 6) {
            f32x4 a[4];
#pragma unroll
            for (int ps = 0; ps < 4; ++ps) a[ps] = (f32x4){0.f, 0.f, 0.f, 0.f};
#pragma unroll
            for (int c0 = 0; c0 < 8; ++c0) {
                const half8 A =
                    woxg[(size_t)((((g * 8 + c0) * 6 + w) * 16 + lo) * 4 + q)];
#pragma unroll
                for (int ps = 0; ps < 4; ++ps) {
                    const half8 B = catx[(c0 * 4 + q) * 64 + ps * 16 + lo];
                    a[ps] = __builtin_amdgcn_mfma_f32_16x16x32_f16(A, B, a[ps], 0, 0, 0);
                }
            }
#pragma unroll
            for (int ps = 0; ps < 4; ++ps) {
#pragma unroll
                for (int r = 0; r < 4; ++r) {
                    const int m = w * 16 + q * 4 + r;
                    if (m < 81)
                        offls[m * 64 + ps * 16 + lo] = (_Float16)a[ps][r];
                }
            }
        }
        __syncthreads();

        // ---- offsets -> registers (frees offls space for sampx) ----
        float offv[7][3];
#pragma unroll
        for (int r = 0; r < 7; ++r) {
            const int tap = r * 4 + t2;
            if (tap < K3) {
#pragma unroll
                for (int c = 0; c < 3; ++c)
                    offv[r][c] = (float)offls[(tap * 3 + c) * 64 + tp];
            }
        }
        __syncthreads();

        // ---- 7 rounds x (sample 4 taps -> barrier -> MFMA 2 pairs) ----
#pragma unroll
        for (int r = 0; r < 7; ++r) {
            half8* dbuf = sampx + (r & 1) * 544;
            const int tap = r * 4 + t2;
            if (tap < K3) {
                const int kz = tap / 9 - 1;
                const int ky = (tap / 3) % 3 - 1;
                const int kx = (tap % 3) - 1;
                const float z = (float)(zoA + kz) + offv[r][0];
                const float y = (float)(yoA + ky) + offv[r][1];
                const float x = (float)(xoA + kx) + offv[r][2];
                const float zf = floorf(z), yf = floorf(y), xf = floorf(x);
                const float fz = z - zf, fy = y - yf, fx = x - xf;
                const int z0i = (int)zf, y0i = (int)yf, x0i = (int)xf;

                const float wz0 = ((unsigned)z0i < DD) ? 1.f - fz : 0.f;
                const float wz1 = ((unsigned)(z0i + 1) < DD) ? fz : 0.f;
                const float wy0 = ((unsigned)y0i < DH) ? 1.f - fy : 0.f;
                const float wy1 = ((unsigned)(y0i + 1) < DH) ? fy : 0.f;
                const float wx0 = ((unsigned)x0i < DW) ? 1.f - fx : 0.f;
                const float wx1 = ((unsigned)(x0i + 1) < DW) ? fx : 0.f;
                float wcs[8];
                wcs[0] = wz0 * wy0 * wx0; wcs[1] = wz0 * wy0 * wx1;
                wcs[2] = wz0 * wy1 * wx0; wcs[3] = wz0 * wy1 * wx1;
                wcs[4] = wz1 * wy0 * wx0; wcs[5] = wz1 * wy0 * wx1;
                wcs[6] = wz1 * wy1 * wx0; wcs[7] = wz1 * wy1 * wx1;

                const int sz0 = z0i - (Z4 - 3);
                const int sy0 = y0i - (Y4 - 3);
                const int sx0 = x0i - (X4 - 3);

                __align__(16) __half2 acch[4];
#pragma unroll
                for (int rr = 0; rr < 4; ++rr) acch[rr] = __floats2half2_rn(0.f, 0.f);

                if ((unsigned)sz0 <= 7u && (unsigned)sy0 <= 8u &&
                    (unsigned)sx0 <= 8u) {
                    // LDS region gather, swizzled half placement
                    const int v000 = (sz0 * 10 + sy0) * 10 + sx0;
                    const int vox[8] = {v000,       v000 + 1,
                                        v000 + 10,  v000 + 11,
                                        v000 + 100, v000 + 101,
                                        v000 + 110, v000 + 111};
                    half8 hv[8];
#pragma unroll
                    for (int ci = 0; ci < 8; ++ci) {
                        const int sw = (h ^ (vox[ci] >> 2)) & 1;
                        hv[ci] = *(const half8*)(regB + vox[ci] * 32 + sw * 16);
                    }
#pragma unroll
                    for (int ci = 0; ci < 8; ++ci) {
                        const __half2 wh = __float2half2_rn(wcs[ci]);
                        const __half2* h2 = (const __half2*)&hv[ci];
#pragma unroll
                        for (int rr = 0; rr < 4; ++rr)
                            acch[rr] = __hfma2(h2[rr], wh, acch[rr]);
                    }
                } else {
                    // exact global fallback (rare)
                    const int iz0 = min(max(z0i, 0), DD - 1);
                    const int iz1 = min(max(z0i + 1, 0), DD - 1);
                    const int iy0 = min(max(y0i, 0), DH - 1);
                    const int iy1 = min(max(y0i + 1, 0), DH - 1);
                    const int ix0 = min(max(x0i, 0), DW - 1);
                    const int ix1 = min(max(x0i + 1, 0), DW - 1);
                    const int v000 = (iz0 << 10) + (iy0 << 5) + ix0;
                    const int dzo = (iz1 - iz0) << 10;
                    const int dyo = (iy1 - iy0) << 5;
                    const int dxo = ix1 - ix0;
                    const int vox[8] = {v000,             v000 + dxo,
                                        v000 + dyo,       v000 + dyo + dxo,
                                        v000 + dzo,       v000 + dzo + dxo,
                                        v000 + dzo + dyo, v000 + dzo + dyo + dxo};
                    const float4* baseF =
                        up4 + (size_t)((b * GG + g) * 2 + h) * PP;
#pragma unroll
                    for (int ci = 0; ci < 8; ++ci) {
                        const float4 u = baseF[vox[ci]];
                        const __half2 wh = __float2half2_rn(wcs[ci]);
                        const __half2* h2 = (const __half2*)&u;
#pragma unroll
                        for (int rr = 0; rr < 4; ++rr)
                            acch[rr] = __hfma2(h2[rr], wh, acch[rr]);
                    }
                }
                dbuf[(t2 * 2 + h) * SROW + tp + (tp >> 4)] = *(half8*)&acch[0];
            }
            __syncthreads();

            // ---- MFMA: wave w = o-tile w; 2 pairs x 4 p-subtiles ----
#pragma unroll
            for (int p = 0; p < 2; ++p) {
                const half8 A = wtx2[(size_t)(
                    (((g * 14 + r * 2 + p) * 8 + w) * 16 + lo) * 4 + q)];
#pragma unroll
                for (int ps = 0; ps < 4; ++ps) {
                    const half8 B = dbuf[(p * 4 + q) * SROW + ps * 17 + lo];
                    acc[ps] = __builtin_amdgcn_mfma_f32_16x16x32_f16(A, B, acc[ps], 0, 0, 0);
                }
            }
        }
    }

    // ---- epilogue: ReLU + store (cube addressing) ----
#pragma unroll
    for (int ps = 0; ps < 4; ++ps) {
        const int zo = Z4 + ps, yo = Y4 + ((lo >> 2) & 3), xo = X4 + (lo & 3);
        const int paddr = (zo << 10) + (yo << 5) + xo;
#pragma unroll
        for (int r = 0; r < 4; ++r) {
            const int o = w * 16 + q * 4 + r;
            out[((size_t)(b * CDN + o) << 14) + paddr] = fmaxf(acc[ps][r], 0.f);
        }
    }
}

// ---------------------------------------------------------------------------
extern "C" void kernel_launch(void* const* d_in, const int* in_sizes, int n_in,
                              void* d_out, int out_size, void* d_ws, size_t ws_size,
                              hipStream_t stream)
{
    const float* src1x = (const float*)d_in[0];   // [2,128,8,16,16]
    const float* dst2x = (const float*)d_in[1];   // [2,128,16,32,32]
    const float* w_off = (const float*)d_in[2];   // [648,256]
    const float* w_dcn = (const float*)d_in[3];   // [128,128,3,3,3]
    float* out = (float*)d_out;

    char* ws = (char*)d_ws;
    half8* uph8 = (half8*)(ws);                    // 8,388,608 B
    half8* woxg = (half8*)(ws + 8388608);          //   393,216 B
    half8* wtx2 = (half8*)(ws + 8781824);          //   917,504 B

    prep_kernel<<<dim3(832), dim3(256), 0, stream>>>(
        src1x, w_off, w_dcn, uph8, woxg, wtx2);
    mega_kernel<<<dim3(256, BB), dim3(512), 0, stream>>>(
        dst2x, (const float4*)uph8, woxg, wtx2, out);
}

// Round 12
// 208.072 us; speedup vs baseline: 1.0696x; 1.0696x over previous
//
#include <hip/hip_runtime.h>
#include <hip/hip_fp16.h>
#include <math.h>

// Problem constants
#define BB   2
#define CSN  128
#define CDN  128
#define SD   8
#define SH   16
#define SW   16
#define DD   16
#define DH   32
#define DW   32
#define PP   (DD*DH*DW)   // 16384
#define GG   8
#define K3   27
#define OO   648

typedef _Float16 half8 __attribute__((ext_vector_type(8)));
typedef float f32x4 __attribute__((ext_vector_type(4)));

// ---------------------------------------------------------------------------
// Kernel 1: PREP — upsample + weight packs (identical to R10).
// ---------------------------------------------------------------------------
__global__ __launch_bounds__(256) void prep_kernel(
    const float* __restrict__ src, const float* __restrict__ wof,
    const float* __restrict__ wdcn, half8* __restrict__ uph8,
    half8* __restrict__ woxg, half8* __restrict__ wtx2)
{
    __shared__ float slab[2 * 8 * 16 * 17];
    const int bid = blockIdx.x;
    const int tid = threadIdx.x;

    if (bid < 512) {
        const int zo = bid & 15, pl = bid >> 4;
        const int h = pl & 1, g = (pl >> 1) & 7, b = pl >> 4;
        const int z0 = (zo - 1) >> 1;
        const float fz = (zo & 1) ? 0.25f : 0.75f;
        {
            const int zi = tid >> 7, cc = (tid >> 4) & 7, y = tid & 15;
            const int zsrc = min(max(z0 + zi, 0), SD - 1);
            const float* srow = src +
                (((size_t)(b * CSN + g * 16 + h * 8 + cc) * SD + zsrc) * SH + y) * SW;
            float* drow = &slab[((zi * 8 + cc) * 16 + y) * 17];
            *(float4*)(drow)      = *(const float4*)(srow);
            *(float4*)(drow + 4)  = *(const float4*)(srow + 4);
            *(float4*)(drow + 8)  = *(const float4*)(srow + 8);
            *(float4*)(drow + 12) = *(const float4*)(srow + 12);
        }
        __syncthreads();

        const float wz0 = 1.f - fz, wz1 = fz;
#pragma unroll 1
        for (int i = 0; i < 4; ++i) {
            const int pp = tid + i * 256;
            const int yo = pp >> 5, xo = pp & 31;
            const int y0 = (yo - 1) >> 1;
            const float fy = (yo & 1) ? 0.25f : 0.75f;
            const int ys0 = max(y0, 0), ys1 = min(y0 + 1, SH - 1);
            const int x0 = (xo - 1) >> 1;
            const float fx = (xo & 1) ? 0.25f : 0.75f;
            const int xs0 = max(x0, 0), xs1 = min(x0 + 1, SW - 1);
            const float w00 = (1.f - fy) * (1.f - fx), w01 = (1.f - fy) * fx;
            const float w10 = fy * (1.f - fx),         w11 = fy * fx;
            const int a00 = ys0 * 17 + xs0, a01 = ys0 * 17 + xs1;
            const int a10 = ys1 * 17 + xs0, a11 = ys1 * 17 + xs1;

            half8 hv;
#pragma unroll
            for (int cc = 0; cc < 8; ++cc) {
                const float* pa = &slab[(cc * 16) * 17];
                const float* pb = &slab[((8 + cc) * 16) * 17];
                const float s0 = w00 * pa[a00] + w01 * pa[a01]
                               + w10 * pa[a10] + w11 * pa[a11];
                const float s1 = w00 * pb[a00] + w01 * pb[a01]
                               + w10 * pb[a10] + w11 * pb[a11];
                hv[cc] = (_Float16)(wz0 * s0 + wz1 * s1);
            }
            uph8[(size_t)pl * PP + zo * 1024 + pp] = hv;
        }
    } else if (bid < 608) {
        const int i = (bid - 512) * 256 + tid;     // < 24576
        const int q = i & 3, lo = (i >> 2) & 15;
        const int t6 = i >> 6;
        const int ot = t6 % 6;
        const int gc0 = t6 / 6;
        const int c0 = gc0 & 7, g = gc0 >> 3;
        const int m = ot * 16 + lo;
        half8 hv;
#pragma unroll
        for (int j = 0; j < 8; ++j) hv[j] = (_Float16)0.0f;
        if (m < 81) {
            const int o = g * 81 + m;
            const int c = c0 * 32 + q * 8;
            const float sc = (c >= 128) ? 2.0f : 1.0f;
            const float* wr = wof + (size_t)o * 256 + c;
#pragma unroll
            for (int j = 0; j < 8; ++j) hv[j] = (_Float16)(wr[j] * sc);
        }
        woxg[i] = hv;
    } else {
        const int i = (bid - 608) * 256 + tid;     // < 57344
        const int q = i & 3, lo = (i >> 2) & 15, ot = (i >> 6) & 7;
        const int gp = i >> 9;
        const int pair = gp % 14, g = gp / 14;
        const int tap = pair * 2 + (q >> 1);
        half8 hv;
#pragma unroll
        for (int j = 0; j < 8; ++j) hv[j] = (_Float16)0.0f;
        if (tap < K3) {
            const int o = ot * 16 + lo;
            const int cb = g * 16 + (q & 1) * 8;
            const float* wr = wdcn + ((size_t)(o * CSN + cb)) * K3 + tap;
#pragma unroll
            for (int j = 0; j < 8; ++j) hv[j] = (_Float16)wr[(size_t)j * K3];
        }
        wtx2[i] = hv;
    }
}

// ---------------------------------------------------------------------------
// Kernel 2: MEGA — 4x4x4 cube tile per block, 2 blocks/CU.
// R12: parity bank-swizzle — half h of voxel (x,y,z) lives at
// v*32 + 16*((x+y+z+h)&1); quads = (2v + parity) mod 8 cover all 8 groups
// within each 8-lane service group for gathers AND staging writes.
// LDS: catx 32K | region 28.8K | offls(10.4K) aliased w/ sampx dbuf (17K).
// ---------------------------------------------------------------------------
#define REGB_OFF 32768
#define SH2_OFF  61568
#define LDS_TOTAL 78976
#define SROW 68                 // padded sampx row stride (half8)

__global__ __launch_bounds__(512, 4) void mega_kernel(
    const float* __restrict__ dst, const float4* __restrict__ up4,
    const half8* __restrict__ woxg, const half8* __restrict__ wtx2,
    float* __restrict__ out)
{
    __shared__ __align__(16) char ldsraw[LDS_TOTAL];
    half8* catx = (half8*)ldsraw;
    char* regB = ldsraw + REGB_OFF;
    _Float16* offls = (_Float16*)(ldsraw + SH2_OFF);
    half8* sampx = (half8*)(ldsraw + SH2_OFF);   // dbuf: +0 / +544 half8

    const int tid = threadIdx.x;
    const int b = blockIdx.y;
    const int cb = blockIdx.x;
    const int X4 = (cb & 7) << 2, Y4 = ((cb >> 3) & 7) << 2, Z4 = (cb >> 6) << 2;

    // ---- phase 0: stage catx with cube columns ----
    {
        const int co = tid >> 4, pq = tid & 15;
        const int cz = pq >> 2, cy = pq & 3;
        const int pbase = ((Z4 + cz) << 10) + ((Y4 + cy) << 5) + X4;
        if (co < 16) {                      // dst channels, fp32 -> f16
            const int c = co * 8;
            const float* dp = dst + ((size_t)(b * CDN + c) << 14) + pbase;
            float vv[32];
#pragma unroll
            for (int j = 0; j < 8; ++j)
                *(float4*)&vv[j * 4] = *(const float4*)(dp + ((size_t)j << 14));
#pragma unroll
            for (int i = 0; i < 4; ++i) {
                half8 hh;
#pragma unroll
                for (int j = 0; j < 8; ++j) hh[j] = (_Float16)vv[j * 4 + i];
                catx[co * 64 + pq * 4 + i] = hh;
            }
        } else {                            // upsampled halves: f16 copy
            const int g2 = (co - 16) >> 1, oct = (co - 16) & 1;
            const half8* u8 = (const half8*)up4;
            const size_t base =
                ((size_t)((b * GG + g2) * 2 + oct) << 14) + pbase;
#pragma unroll
            for (int i = 0; i < 4; ++i)
                catx[co * 64 + pq * 4 + i] = u8[base + i];
        }
    }

    const int w = tid >> 6, l = tid & 63, lo = l & 15, q = l >> 4;
    const int t2 = w >> 1, h = w & 1;       // sampling: tap-in-round, ch-half
    const int tp = l;                       // cube column
    const int cz = tp >> 4, cy = (tp >> 2) & 3, cx = tp & 3;
    const int zoA = Z4 + cz, yoA = Y4 + cy, xoA = X4 + cx;

    f32x4 acc[4];
#pragma unroll
    for (int ps = 0; ps < 4; ++ps) acc[ps] = (f32x4){0.f, 0.f, 0.f, 0.f};

#pragma unroll 1
    for (int g = 0; g < 8; ++g) {
        __syncthreads();    // prior rounds done reading regB / sampx(offls)

        // ---- region staging: interleaved (hf = c&1), parity-swizzled ----
#pragma unroll 1
        for (int c = tid; c < 1800; c += 512) {
            const int hf = c & 1;
            const int v = c >> 1;
            const int zz = v / 100, r2 = v - zz * 100;
            const int yy = r2 / 10, xx = r2 - yy * 10;
            const int vz = min(max(Z4 - 3 + zz, 0), DD - 1);
            const int vy = min(max(Y4 - 3 + yy, 0), DH - 1);
            const int vx = min(max(X4 - 3 + xx, 0), DW - 1);
            const float4 val =
                up4[(size_t)((b * GG + g) * 2 + hf) * PP +
                    (vz << 10) + (vy << 5) + vx];
            const int sw = (xx + yy + zz + hf) & 1;      // parity swizzle
            *(float4*)(regB + v * 32 + sw * 16) = val;
        }

        // ---- phase A: offset mini-GEMM, A reused across all 4 ps ----
        if (w < 6) {
            f32x4 a[4];
#pragma unroll
            for (int ps = 0; ps < 4; ++ps) a[ps] = (f32x4){0.f, 0.f, 0.f, 0.f};
#pragma unroll
            for (int c0 = 0; c0 < 8; ++c0) {
                const half8 A =
                    woxg[(size_t)((((g * 8 + c0) * 6 + w) * 16 + lo) * 4 + q)];
#pragma unroll
                for (int ps = 0; ps < 4; ++ps) {
                    const half8 B = catx[(c0 * 4 + q) * 64 + ps * 16 + lo];
                    a[ps] = __builtin_amdgcn_mfma_f32_16x16x32_f16(A, B, a[ps], 0, 0, 0);
                }
            }
#pragma unroll
            for (int ps = 0; ps < 4; ++ps) {
#pragma unroll
                for (int r = 0; r < 4; ++r) {
                    const int m = w * 16 + q * 4 + r;
                    if (m < 81)
                        offls[m * 64 + ps * 16 + lo] = (_Float16)a[ps][r];
                }
            }
        }
        __syncthreads();

        // ---- offsets -> registers (frees offls space for sampx) ----
        float offv[7][3];
#pragma unroll
        for (int r = 0; r < 7; ++r) {
            const int tap = r * 4 + t2;
            if (tap < K3) {
#pragma unroll
                for (int c = 0; c < 3; ++c)
                    offv[r][c] = (float)offls[(tap * 3 + c) * 64 + tp];
            }
        }
        __syncthreads();

        // ---- 7 rounds x (sample 4 taps -> barrier -> MFMA 2 pairs) ----
#pragma unroll
        for (int r = 0; r < 7; ++r) {
            half8* dbuf = sampx + (r & 1) * 544;
            const int tap = r * 4 + t2;
            if (tap < K3) {
                const int kz = tap / 9 - 1;
                const int ky = (tap / 3) % 3 - 1;
                const int kx = (tap % 3) - 1;
                const float z = (float)(zoA + kz) + offv[r][0];
                const float y = (float)(yoA + ky) + offv[r][1];
                const float x = (float)(xoA + kx) + offv[r][2];
                const float zf = floorf(z), yf = floorf(y), xf = floorf(x);
                const float fz = z - zf, fy = y - yf, fx = x - xf;
                const int z0i = (int)zf, y0i = (int)yf, x0i = (int)xf;

                const float wz0 = ((unsigned)z0i < DD) ? 1.f - fz : 0.f;
                const float wz1 = ((unsigned)(z0i + 1) < DD) ? fz : 0.f;
                const float wy0 = ((unsigned)y0i < DH) ? 1.f - fy : 0.f;
                const float wy1 = ((unsigned)(y0i + 1) < DH) ? fy : 0.f;
                const float wx0 = ((unsigned)x0i < DW) ? 1.f - fx : 0.f;
                const float wx1 = ((unsigned)(x0i + 1) < DW) ? fx : 0.f;
                float wcs[8];
                wcs[0] = wz0 * wy0 * wx0; wcs[1] = wz0 * wy0 * wx1;
                wcs[2] = wz0 * wy1 * wx0; wcs[3] = wz0 * wy1 * wx1;
                wcs[4] = wz1 * wy0 * wx0; wcs[5] = wz1 * wy0 * wx1;
                wcs[6] = wz1 * wy1 * wx0; wcs[7] = wz1 * wy1 * wx1;

                const int sz0 = z0i - (Z4 - 3);
                const int sy0 = y0i - (Y4 - 3);
                const int sx0 = x0i - (X4 - 3);

                __align__(16) __half2 acch[4];
#pragma unroll
                for (int rr = 0; rr < 4; ++rr) acch[rr] = __floats2half2_rn(0.f, 0.f);

                if ((unsigned)sz0 <= 7u && (unsigned)sy0 <= 8u &&
                    (unsigned)sx0 <= 8u) {
                    // LDS region gather, parity-swizzled half placement
                    const int v000 = (sz0 * 10 + sy0) * 10 + sx0;
                    const int s0 = (sx0 + sy0 + sz0 + h) & 1;   // base parity
                    const int s1 = s0 ^ 1;
                    const int vox[8] = {v000,       v000 + 1,
                                        v000 + 10,  v000 + 11,
                                        v000 + 100, v000 + 101,
                                        v000 + 110, v000 + 111};
                    const int sws[8] = {s0, s1, s1, s0, s1, s0, s0, s1};
                    half8 hv[8];
#pragma unroll
                    for (int ci = 0; ci < 8; ++ci)
                        hv[ci] = *(const half8*)(regB + vox[ci] * 32 + sws[ci] * 16);
#pragma unroll
                    for (int ci = 0; ci < 8; ++ci) {
                        const __half2 wh = __float2half2_rn(wcs[ci]);
                        const __half2* h2 = (const __half2*)&hv[ci];
#pragma unroll
                        for (int rr = 0; rr < 4; ++rr)
                            acch[rr] = __hfma2(h2[rr], wh, acch[rr]);
                    }
                } else {
                    // exact global fallback (rare)
                    const int iz0 = min(max(z0i, 0), DD - 1);
                    const int iz1 = min(max(z0i + 1, 0), DD - 1);
                    const int iy0 = min(max(y0i, 0), DH - 1);
                    const int iy1 = min(max(y0i + 1, 0), DH - 1);
                    const int ix0 = min(max(x0i, 0), DW - 1);
                    const int ix1 = min(max(x0i + 1, 0), DW - 1);
                    const int v000 = (iz0 << 10) + (iy0 << 5) + ix0;
                    const int dzo = (iz1 - iz0) << 10;
                    const int dyo = (iy1 - iy0) << 5;
                    const int dxo = ix1 - ix0;
                    const int vox[8] = {v000,             v000 + dxo,
                                        v000 + dyo,       v000 + dyo + dxo,
                                        v000 + dzo,       v000 + dzo + dxo,
                                        v000 + dzo + dyo, v000 + dzo + dyo + dxo};
                    const float4* baseF =
                        up4 + (size_t)((b * GG + g) * 2 + h) * PP;
#pragma unroll
                    for (int ci = 0; ci < 8; ++ci) {
                        const float4 u = baseF[vox[ci]];
                        const __half2 wh = __float2half2_rn(wcs[ci]);
                        const __half2* h2 = (const __half2*)&u;
#pragma unroll
                        for (int rr = 0; rr < 4; ++rr)
                            acch[rr] = __hfma2(h2[rr], wh, acch[rr]);
                    }
                }
                dbuf[(t2 * 2 + h) * SROW + tp + (tp >> 4)] = *(half8*)&acch[0];
            }
            __syncthreads();

            // ---- MFMA: wave w = o-tile w; 2 pairs x 4 p-subtiles ----
#pragma unroll
            for (int p = 0; p < 2; ++p) {
                const half8 A = wtx2[(size_t)(
                    (((g * 14 + r * 2 + p) * 8 + w) * 16 + lo) * 4 + q)];
#pragma unroll
                for (int ps = 0; ps < 4; ++ps) {
                    const half8 B = dbuf[(p * 4 + q) * SROW + ps * 17 + lo];
                    acc[ps] = __builtin_amdgcn_mfma_f32_16x16x32_f16(A, B, acc[ps], 0, 0, 0);
                }
            }
        }
    }

    // ---- epilogue: ReLU + store (cube addressing) ----
#pragma unroll
    for (int ps = 0; ps < 4; ++ps) {
        const int zo = Z4 + ps, yo = Y4 + ((lo >> 2) & 3), xo = X4 + (lo & 3);
        const int paddr = (zo << 10) + (yo << 5) + xo;
#pragma unroll
        for (int r = 0; r < 4; ++r) {
            const int o = w * 16 + q * 4 + r;
            out[((size_t)(b * CDN + o) << 14) + paddr] = fmaxf(acc[ps][r], 0.f);
        }
    }
}

// ---------------------------------------------------------------------------
extern "C" void kernel_launch(void* const* d_in, const int* in_sizes, int n_in,
                              void* d_out, int out_size, void* d_ws, size_t ws_size,
                              hipStream_t stream)
{
    const float* src1x = (const float*)d_in[0];   // [2,128,8,16,16]
    const float* dst2x = (const float*)d_in[1];   // [2,128,16,32,32]
    const float* w_off = (const float*)d_in[2];   // [648,256]
    const float* w_dcn = (const float*)d_in[3];   // [128,128,3,3,3]
    float* out = (float*)d_out;

    char* ws = (char*)d_ws;
    half8* uph8 = (half8*)(ws);                    // 8,388,608 B
    half8* woxg = (half8*)(ws + 8388608);          //   393,216 B
    half8* wtx2 = (half8*)(ws + 8781824);          //   917,504 B

    prep_kernel<<<dim3(832), dim3(256), 0, stream>>>(
        src1x, w_off, w_dcn, uph8, woxg, wtx2);
    mega_kernel<<<dim3(256, BB), dim3(512), 0, stream>>>(
        dst2x, (const float4*)uph8, woxg, wtx2, out);
}